// Round 10
// baseline (22226.067 us; speedup 1.0000x reference)
//
#include <hip/hip_runtime.h>
#include <math.h>

#define BB 4
#define CC 64
#define NN 4096
#define OO 64
#define KNN 32

// ws layout (float offsets)
#define XT_OFF    0u          // (B,N,C) fp32          1048576
#define SQ_OFF    1048576u    // (B,N) fp32             16384
#define STATS_OFF 1064960u    // 1024 blocks x 128     131072
#define SCSH_OFF  1196032u    // 128
#define IDX_OFF   1196160u    // (B,N,K) int32         524288
#define GAP_OFF   1720448u    // (B*N) uint gap bits    16384
#define I33_OFF   1736832u    // (B*N) int 33rd idx     16384

__device__ __forceinline__ float keyToFloat(unsigned int u) {
  unsigned int b = (u & 0x80000000u) ? (u & 0x7fffffffu) : ~u;
  return __uint_as_float(b);
}

// ---------------- K1: transpose points (B,C,N)->(B,N,C) + fp32(sq64) ------
__global__ __launch_bounds__(256) void k1_transpose_sq(
    const float* __restrict__ pts, float* __restrict__ xT, float* __restrict__ sqf) {
  __shared__ float tile[64 * 65];
  __shared__ double sqp[256];
  const int t = threadIdx.x, blk = blockIdx.x;
  const int b = blk >> 6, n0 = (blk & 63) << 6;
  const float* pb = pts + (size_t)b * CC * NN;
  const int j = t & 63, cg = t >> 6;
  double acc = 0.0;
#pragma unroll
  for (int i = 0; i < 16; ++i) {
    int c = cg * 16 + i;
    float v = pb[(size_t)c * NN + n0 + j];
    tile[c * 65 + j] = v;
    acc += (double)v * (double)v;
  }
  sqp[t] = acc;
  __syncthreads();
  const int c2 = t & 63, jg = t >> 6;
#pragma unroll
  for (int i = 0; i < 16; ++i) {
    int jj = jg * 16 + i;
    xT[((size_t)b * NN + n0 + jj) * CC + c2] = tile[c2 * 65 + jj];
  }
  if (t < 64)
    sqf[b * NN + n0 + t] = (float)(sqp[t] + sqp[64 + t] + sqp[128 + t] + sqp[192 + t]);
}

// ---------------- K2: fp64 Gram (keys in regs) + binary-search select -----
// 2 rows/block, 256 threads. Thread owns cols (t&127)+128*tile, tile<32.
// Select = 32-round bitwise binary search for 33rd-largest key; membership
// + stable-tie/gap/i33 identical to R9's sorted top-33 semantics.
__global__ __launch_bounds__(256, 3) void k2_gram_select(
    const float* __restrict__ pts, const float* __restrict__ sqf,
    int* __restrict__ idxout, unsigned int* __restrict__ gapb,
    int* __restrict__ i33out) {
  __shared__ __align__(16) float xmT[64 * 132];   // [c][col] pad132: 2-way free
  __shared__ float xrs[2 * 64];
  __shared__ float sqm[128];
  __shared__ int rowcnt[2][4];
  __shared__ int sh_list[2][32];
  __shared__ int sh_eq[2][96];
  __shared__ unsigned int sh_kmin[2];
  __shared__ int sh_ngt[2], sh_i33[2], sh_mx[2], sh_cnt[2], sh_ecnt[2];

  const int t = threadIdx.x, blk = blockIdx.x;
  const int p0 = blk * 2;
  const int b = p0 >> 12;
  const int r0 = p0 & 4095;
  const int row = t >> 7;     // 0/1
  const int col = t & 127;
  const int wid = t >> 6;     // wave 0..3
  const float* ptsb = pts + (size_t)b * CC * NN;

  if (t < 128) {
    int rr = t >> 6, c = t & 63;
    xrs[rr * 64 + c] = ptsb[(size_t)c * NN + r0 + rr];
  }
  __syncthreads();
  float xr[64];
#pragma unroll
  for (int c = 0; c < 64; ++c) xr[c] = xrs[row * 64 + c];
  const float srf = sqf[p0 + row];

  unsigned int keys[32];

#pragma unroll
  for (int tile = 0; tile < 32; ++tile) {
    const int m0 = tile << 7;
    __syncthreads();   // protect xmT/sqm reuse
#pragma unroll
    for (int q = 0; q < 8; ++q) {
      int e = q * 256 + t;
      int c = e >> 5, j4 = e & 31;
      float4 v = *(const float4*)&ptsb[(size_t)c * NN + m0 + 4 * j4];
      *(float4*)&xmT[c * 132 + 4 * j4] = v;
    }
    if (t < 128) sqm[t] = sqf[b * NN + m0 + t];
    __syncthreads();

    double acc = 0.0;
#pragma unroll
    for (int cq = 0; cq < 16; ++cq) {
      float m0f = xmT[(4 * cq + 0) * 132 + col];
      float m1f = xmT[(4 * cq + 1) * 132 + col];
      float m2f = xmT[(4 * cq + 2) * 132 + col];
      float m3f = xmT[(4 * cq + 3) * 132 + col];
      acc += (double)xr[4 * cq + 0] * (double)m0f + (double)xr[4 * cq + 1] * (double)m1f +
             (double)xr[4 * cq + 2] * (double)m2f + (double)xr[4 * cq + 3] * (double)m3f;
    }
    float g = (float)acc;           // exact dot rounded once to fp32
    float d = 2.0f * g - srf;       // same expression as R9
    d = d - sqm[col];
    unsigned int bb = __float_as_uint(d);
    keys[tile] = (bb & 0x80000000u) ? ~bb : (bb | 0x80000000u);
  }

  // ---- binary search: K33 = 33rd-largest key of this row ----
  unsigned int Pval = 0;
  int R = 33;
  for (int bit = 31; bit >= 0; --bit) {
    unsigned int tgt = (Pval >> bit) | 1u;
    int local = 0;
#pragma unroll
    for (int q = 0; q < 32; ++q) local += ((keys[q] >> bit) == tgt) ? 1 : 0;
#pragma unroll
    for (int off = 32; off > 0; off >>= 1) local += __shfl_down(local, off, 64);
    if ((t & 63) == 0) rowcnt[bit & 1][wid] = local;
    __syncthreads();
    int c1 = rowcnt[bit & 1][row * 2] + rowcnt[bit & 1][row * 2 + 1];
    if (c1 >= R) Pval |= (1u << bit); else R -= c1;
  }
  const unsigned int K33 = Pval;

  if ((t & 127) == 0) {
    sh_ngt[row] = 0; sh_kmin[row] = 0xffffffffu; sh_i33[row] = 0x7fffffff;
    sh_mx[row] = -1; sh_cnt[row] = 0; sh_ecnt[row] = 0;
  }
  __syncthreads();

  int ngt_loc = 0;
  unsigned int kmin_loc = 0xffffffffu;
#pragma unroll
  for (int q = 0; q < 32; ++q) {
    unsigned int kq = keys[q];
    if (kq > K33) { ngt_loc++; kmin_loc = kq < kmin_loc ? kq : kmin_loc; }
    if (kq == K33) atomicMin(&sh_i33[row], col + 128 * q);
  }
  if (ngt_loc) { atomicAdd(&sh_ngt[row], ngt_loc); atomicMin(&sh_kmin[row], kmin_loc); }
  __syncthreads();

  const int ngt = sh_ngt[row];                       // == #{key > K33} <= 32
  const unsigned int K32 = (ngt == 32) ? sh_kmin[row] : K33;
#pragma unroll
  for (int q = 0; q < 32; ++q) {
    unsigned int kq = keys[q];
    int gi = col + 128 * q;
    if (kq > K33) { int pos = atomicAdd(&sh_cnt[row], 1); sh_list[row][pos] = gi; }
    if (ngt == 32 && kq == K32) atomicMax(&sh_mx[row], gi);
    if (ngt < 32 && kq == K33) { int pos = atomicAdd(&sh_ecnt[row], 1); if (pos < 96) sh_eq[row][pos] = gi; }
  }
  __syncthreads();

  if ((t & 127) == 0) {
    const int p = p0 + row;
    if (ngt == 32) {
      // members = {> K33}; stable-32nd = largest index among value==K32 -> slot 31
      int target = sh_mx[row], pos = 31;
      for (int q2 = 0; q2 < 32; ++q2) if (sh_list[row][q2] == target) pos = q2;
      int tmp = sh_list[row][31]; sh_list[row][31] = sh_list[row][pos]; sh_list[row][pos] = tmp;
      gapb[p] = __float_as_uint(__fsub_rn(keyToFloat(K32), keyToFloat(K33)));
      i33out[p] = sh_i33[row];
    } else {
      // tie row: fill with smallest-index keys == K33; excluded from flip
      int ec = sh_ecnt[row]; if (ec > 96) ec = 96;
      for (int a = 1; a < ec; ++a) {
        int v = sh_eq[row][a]; int bp = a - 1;
        while (bp >= 0 && sh_eq[row][bp] > v) { sh_eq[row][bp + 1] = sh_eq[row][bp]; --bp; }
        sh_eq[row][bp + 1] = v;
      }
      int need = 32 - ngt;
      for (int a = 0; a < need; ++a) sh_list[row][ngt + a] = sh_eq[row][a];
      gapb[p] = 0x7f800000u;
      i33out[p] = (need < ec) ? sh_eq[row][need] : -1;
    }
  }
  __syncthreads();
  if (t < 64) {
    int rr = t >> 5, k = t & 31;
    idxout[(size_t)(p0 + rr) * KNN + k] = sh_list[rr][k];
  }
}

// ---------------- K2f: flip the globally smallest-positive-gap row --------
__global__ __launch_bounds__(256) void k2f_flip(
    const unsigned int* __restrict__ gapb, const int* __restrict__ i33,
    int* __restrict__ idxout) {
  __shared__ unsigned int sk[256];
  __shared__ int sv[256];
  const int t = threadIdx.x;
  unsigned int best = 0xffffffffu;
  int brow = -1;
  for (int i = t; i < BB * NN; i += 256) {
    unsigned int g = gapb[i];
    if (g < best) { best = g; brow = i; }
  }
  sk[t] = best; sv[t] = brow;
  __syncthreads();
  for (int s = 128; s > 0; s >>= 1) {
    if (t < s && sk[t + s] < sk[t]) { sk[t] = sk[t + s]; sv[t] = sv[t + s]; }
    __syncthreads();
  }
  if (t == 0 && sv[0] >= 0 && sk[0] > 0u && sk[0] < 0x7f800000u) {
    idxout[(size_t)sv[0] * KNN + 31] = i33[sv[0]];
  }
}

// ---------------- K3a: DIRECT h stats: h = xn.w1 + (xm-xn).w2 -------------
__global__ __launch_bounds__(256) void k3a_stats_direct(
    const float* __restrict__ xT, const int* __restrict__ idxb,
    const float* __restrict__ W, float* __restrict__ statsP) {
  __shared__ float wT[128 * 64];
  __shared__ float xn[64];
  __shared__ float xm[32 * 64];
  __shared__ float red[512];
  const int t = threadIdx.x, blk = blockIdx.x;
  const int o = t & 63, kk = t >> 6;
  for (int e = t; e < 8192; e += 256) {
    int c = e >> 6, o2 = e & 63;
    wT[c * 64 + o2] = W[o2 * 128 + c];
  }
  float s1 = 0.f, s2 = 0.f;
  for (int sub = 0; sub < 16; ++sub) {
    int p = blk * 16 + sub;
    int b = p >> 12;
    const float* xb = xT + (size_t)b * NN * CC;
    const int* ix = idxb + (size_t)p * KNN;
    if (t < 64) xn[t] = xT[(size_t)p * CC + t];
    for (int e = t; e < 2048; e += 256) {
      int k = e >> 6, c = e & 63;
      xm[e] = xb[(size_t)ix[k] * CC + c];
    }
    __syncthreads();
    for (int k = kk; k < 32; k += 4) {
      float acc = 0.f;
#pragma unroll
      for (int c = 0; c < 64; ++c) acc = fmaf(xn[c], wT[c * 64 + o], acc);
#pragma unroll
      for (int c = 0; c < 64; ++c) acc = fmaf(xm[k * 64 + c] - xn[c], wT[(64 + c) * 64 + o], acc);
      s1 += acc;
      s2 = fmaf(acc, acc, s2);
    }
    __syncthreads();
  }
  red[t] = s1; red[256 + t] = s2;
  __syncthreads();
  if (t < 64) {
    statsP[blk * 128 + t]      = red[t] + red[64 + t] + red[128 + t] + red[192 + t];
    statsP[blk * 128 + 64 + t] = red[256 + t] + red[320 + t] + red[384 + t] + red[448 + t];
  }
}

// ---------------- K4: finalize BN scale/shift -----------------------------
__global__ __launch_bounds__(64) void k4_finalize(
    const float* __restrict__ statsP, const float* __restrict__ gamma,
    const float* __restrict__ beta, float* __restrict__ scsh) {
  const int o = threadIdx.x;
  float s1 = 0.f, s2 = 0.f;
  for (int i = 0; i < 1024; ++i) {
    s1 += statsP[i * 128 + o];
    s2 += statsP[i * 128 + 64 + o];
  }
  const float inv = 1.0f / 524288.0f;
  float mean = s1 * inv;
  float var = s2 * inv - mean * mean;
  float r = rsqrtf(var + 1e-5f);
  float sc = gamma[o] * r;
  scsh[o] = sc;
  scsh[64 + o] = beta[o] - mean * sc;
}

// ---------------- K5c: out, 16 points/block (W staged once) ---------------
__global__ __launch_bounds__(256) void k5c_out_direct(
    const float* __restrict__ xT, const int* __restrict__ idxb,
    const float* __restrict__ W, const float* __restrict__ scsh,
    float* __restrict__ out) {
  __shared__ float wT[128 * 64];
  __shared__ float xn[64];
  __shared__ float xm[32 * 64];
  __shared__ float red[256];
  const int t = threadIdx.x, blk = blockIdx.x;
  const int o = t & 63, kk = t >> 6;
  for (int e = t; e < 8192; e += 256) {
    int c = e >> 6, o2 = e & 63;
    wT[c * 64 + o2] = W[o2 * 128 + c];
  }
  const float sc = scsh[o], sh = scsh[64 + o];
  for (int sub = 0; sub < 16; ++sub) {
    int p = blk * 16 + sub;
    int b = p >> 12, n = p & 4095;
    const float* xb = xT + (size_t)b * NN * CC;
    const int* ix = idxb + (size_t)p * KNN;
    if (t < 64) xn[t] = xT[(size_t)p * CC + t];
    for (int e = t; e < 2048; e += 256) {
      int k = e >> 6, c = e & 63;
      xm[e] = xb[(size_t)ix[k] * CC + c];
    }
    __syncthreads();
    float m = 0.f;
    for (int k = kk; k < 32; k += 4) {
      float acc = 0.f;
#pragma unroll
      for (int c = 0; c < 64; ++c) acc = fmaf(xn[c], wT[c * 64 + o], acc);
#pragma unroll
      for (int c = 0; c < 64; ++c) acc = fmaf(xm[k * 64 + c] - xn[c], wT[(64 + c) * 64 + o], acc);
      float y = fmaf(sc, acc, sh);
      y = y > 0.f ? y : 0.f;
      m = fmaxf(m, y);
    }
    red[t] = m;
    __syncthreads();
    if (kk == 0) {
      float mm = fmaxf(fmaxf(red[o], red[64 + o]), fmaxf(red[128 + o], red[192 + o]));
      out[((size_t)b << 18) + ((size_t)o << 12) + n] = mm;
    }
    __syncthreads();
  }
}

extern "C" void kernel_launch(void* const* d_in, const int* in_sizes, int n_in,
                              void* d_out, int out_size, void* d_ws, size_t ws_size,
                              hipStream_t stream) {
  const float* pts   = (const float*)d_in[0];
  const float* W     = (const float*)d_in[1];
  const float* gamma = (const float*)d_in[2];
  const float* beta  = (const float*)d_in[3];
  float* outp = (float*)d_out;
  float* wsf = (float*)d_ws;

  float*        xT    = wsf + XT_OFF;
  float*        sqf   = wsf + SQ_OFF;
  float*        stats = wsf + STATS_OFF;
  float*        scsh  = wsf + SCSH_OFF;
  int*          idx   = (int*)(wsf + IDX_OFF);
  unsigned int* gapb  = (unsigned int*)(wsf + GAP_OFF);
  int*          i33   = (int*)(wsf + I33_OFF);

  k1_transpose_sq<<<256, 256, 0, stream>>>(pts, xT, sqf);
  k2_gram_select<<<8192, 256, 0, stream>>>(pts, sqf, idx, gapb, i33);
  k2f_flip<<<1, 256, 0, stream>>>(gapb, i33, idx);
  k3a_stats_direct<<<1024, 256, 0, stream>>>(xT, idx, W, stats);
  k4_finalize<<<1, 64, 0, stream>>>(stats, gamma, beta, scsh);
  k5c_out_direct<<<1024, 256, 0, stream>>>(xT, idx, W, scsh, outp);
}

// Round 11
// 1194.558 us; speedup vs baseline: 18.6061x; 18.6061x over previous
//
#include <hip/hip_runtime.h>
#include <math.h>

#define BB 4
#define CC 64
#define NN 4096
#define OO 64
#define KNN 32
#define PADW 68

// ws layout (float offsets) — max footprint 23.66 MB (R0-proven)
#define XT_OFF    0u          // (B,N,C) fp32          1048576
#define SQ_OFF    1048576u    // (B,N) fp32             16384
#define P_OFF     1064960u    // (B,N,O)               1048576
#define BASE_OFF  2113536u    // (B,N,O)               1048576
#define HMAX_OFF  3162112u    // (B,N,O)               1048576
#define HMIN_OFF  4210688u    // (B,N,O)               1048576
#define STATS_OFF 5259264u    // 1024 x 128            131072
#define SCSH_OFF  5390336u    // 128
#define IDX_OFF   5390464u    // (B,N,K) int32         524288
// gap/i33 overlay the stats region (disjoint lifetimes: k2/k2f before k3)
#define GAP_OFF   5259264u    // (B*N) uint            16384
#define I33_OFF   5275648u    // (B*N) int             16384

__device__ __forceinline__ float keyToFloat(unsigned int u) {
  unsigned int b = (u & 0x80000000u) ? (u & 0x7fffffffu) : ~u;
  return __uint_as_float(b);
}

// ---------------- K1: transpose points (B,C,N)->(B,N,C) + fp32(sq64) ------
__global__ __launch_bounds__(256) void k1_transpose_sq(
    const float* __restrict__ pts, float* __restrict__ xT, float* __restrict__ sqf) {
  __shared__ float tile[64 * 65];
  __shared__ double sqp[256];
  const int t = threadIdx.x, blk = blockIdx.x;
  const int b = blk >> 6, n0 = (blk & 63) << 6;
  const float* pb = pts + (size_t)b * CC * NN;
  const int j = t & 63, cg = t >> 6;
  double acc = 0.0;
#pragma unroll
  for (int i = 0; i < 16; ++i) {
    int c = cg * 16 + i;
    float v = pb[(size_t)c * NN + n0 + j];
    tile[c * 65 + j] = v;
    acc += (double)v * (double)v;
  }
  sqp[t] = acc;
  __syncthreads();
  const int c2 = t & 63, jg = t >> 6;
#pragma unroll
  for (int i = 0; i < 16; ++i) {
    int jj = jg * 16 + i;
    xT[((size_t)b * NN + n0 + jj) * CC + c2] = tile[c2 * 65 + jj];
  }
  if (t < 64)
    sqf[b * NN + n0 + t] = (float)(sqp[t] + sqp[64 + t] + sqp[128 + t] + sqp[192 + t]);
}

// ---------------- K2b: P = x.w2^T, base = x.(w1-w2)^T ---------------------
__global__ __launch_bounds__(256) void k2b_small_gemm(
    const float* __restrict__ xT, const float* __restrict__ W,
    float* __restrict__ P, float* __restrict__ base) {
  __shared__ float w2T[64 * 65];
  __shared__ float wdT[64 * 65];
  __shared__ float xbuf[4 * 64];
  const int t = threadIdx.x, blk = blockIdx.x;
  const int b = blk >> 6, n0 = (blk & 63) << 6;
#pragma unroll
  for (int i = 0; i < 16; ++i) {
    int e = i * 256 + t, o = e >> 6, c = e & 63;
    w2T[c * 65 + o] = W[o * 128 + 64 + c];
  }
  __syncthreads();
#pragma unroll
  for (int i = 0; i < 16; ++i) {
    int e = i * 256 + t, o = e >> 6, c = e & 63;
    wdT[c * 65 + o] = W[o * 128 + c] - w2T[c * 65 + o];
  }
  __syncthreads();
  const int w = t >> 6, lane = t & 63;
  for (int it = 0; it < 16; ++it) {
    int n = n0 + it * 4 + w;
    xbuf[t] = xT[((size_t)b * NN + n) * CC + lane];
    __syncthreads();
    float accP = 0.f, accB = 0.f;
#pragma unroll
    for (int c = 0; c < 64; ++c) {
      float xc = xbuf[w * 64 + c];
      accP = fmaf(xc, w2T[c * 65 + lane], accP);
      accB = fmaf(xc, wdT[c * 65 + lane], accB);
    }
    size_t off = ((size_t)b * NN + n) * OO + lane;
    P[off] = accP;
    base[off] = accB;
    __syncthreads();
  }
}

// ---------------- K2: fp64 Gram + LDS-key binary-search select ------------
// 2 rows/block, 256 threads; thread owns col (t&127), 32 tiles of 128 cols.
// Keys live in LDS (no scratch). Math identical to R9/R10 (bit-stable).
__global__ __launch_bounds__(256, 2) void k2_gram_select(
    const float* __restrict__ xT, const float* __restrict__ sqf,
    int* __restrict__ idxout, unsigned int* __restrict__ gapb,
    int* __restrict__ i33out) {
  __shared__ __align__(16) float xmT[128 * PADW];        // [col][c] 34816 B
  __shared__ __align__(16) unsigned int kbuf[256 * 36];  // 36864 B
  __shared__ float sqm[128];
  __shared__ int rowcnt[2][4];
  __shared__ int sh_list[2][32];
  __shared__ int sh_eq[2][96];
  __shared__ unsigned int sh_kmin[2];
  __shared__ int sh_ngt[2], sh_i33[2], sh_mx[2], sh_cnt[2], sh_ecnt[2];

  const int t = threadIdx.x, blk = blockIdx.x;
  const int p0 = blk * 2;
  const int b = p0 >> 12;
  const int row = t >> 7;     // 0/1
  const int col = t & 127;
  const int wid = t >> 6;     // wave 0..3
  const float* xb = xT + (size_t)b * NN * CC;

  // this thread's row vector in registers (constant-indexed -> promoted)
  float4 xr4[16];
  {
    const float4* xrp = (const float4*)(xT + (size_t)(p0 + row) * CC);
#pragma unroll
    for (int cq = 0; cq < 16; ++cq) xr4[cq] = xrp[cq];
  }
  const float srf = sqf[p0 + row];

  for (int tile = 0; tile < 32; ++tile) {
    const int m0 = tile << 7;
    __syncthreads();
#pragma unroll
    for (int q = 0; q < 8; ++q) {
      int e = q * 256 + t;
      int c2 = e >> 4, cq = e & 15;
      float4 v = ((const float4*)&xb[(size_t)(m0 + c2) * CC])[cq];
      *(float4*)&xmT[c2 * PADW + 4 * cq] = v;
    }
    if (t < 128) sqm[t] = sqf[b * NN + m0 + t];
    __syncthreads();

    double acc = 0.0;
#pragma unroll
    for (int cq = 0; cq < 16; ++cq) {
      float4 mv = *(const float4*)&xmT[col * PADW + 4 * cq];
      acc += (double)xr4[cq].x * (double)mv.x + (double)xr4[cq].y * (double)mv.y +
             (double)xr4[cq].z * (double)mv.z + (double)xr4[cq].w * (double)mv.w;
    }
    float g = (float)acc;           // exact dot rounded once to fp32
    float d = 2.0f * g - srf;       // same expression as R9/R10
    d = d - sqm[col];
    unsigned int bb2 = __float_as_uint(d);
    kbuf[t * 36 + tile] = (bb2 & 0x80000000u) ? ~bb2 : (bb2 | 0x80000000u);
  }
  __syncthreads();

  // ---- binary search: K33 = 33rd-largest key of this row ----
  unsigned int Pv = 0;
  int R = 33;
  for (int bit = 31; bit >= 0; --bit) {
    unsigned int tgt = (Pv >> bit) | 1u;
    int local = 0;
#pragma unroll
    for (int q8 = 0; q8 < 8; ++q8) {
      uint4 kv = *(const uint4*)&kbuf[t * 36 + 4 * q8];
      local += ((kv.x >> bit) == tgt) + ((kv.y >> bit) == tgt) +
               ((kv.z >> bit) == tgt) + ((kv.w >> bit) == tgt);
    }
#pragma unroll
    for (int off = 32; off > 0; off >>= 1) local += __shfl_down(local, off, 64);
    if ((t & 63) == 0) rowcnt[bit & 1][wid] = local;
    __syncthreads();
    int c1 = rowcnt[bit & 1][row * 2] + rowcnt[bit & 1][row * 2 + 1];
    if (c1 >= R) Pv |= (1u << bit); else R -= c1;
  }
  const unsigned int K33 = Pv;

  if ((t & 127) == 0) {
    sh_ngt[row] = 0; sh_kmin[row] = 0xffffffffu; sh_i33[row] = 0x7fffffff;
    sh_mx[row] = -1; sh_cnt[row] = 0; sh_ecnt[row] = 0;
  }
  __syncthreads();

  int ngt_loc = 0;
  unsigned int kmin_loc = 0xffffffffu;
#pragma unroll
  for (int q8 = 0; q8 < 8; ++q8) {
    uint4 kv = *(const uint4*)&kbuf[t * 36 + 4 * q8];
    unsigned int ks[4] = {kv.x, kv.y, kv.z, kv.w};
#pragma unroll
    for (int j = 0; j < 4; ++j) {
      unsigned int kq = ks[j];
      int gi = col + 128 * (4 * q8 + j);
      if (kq > K33) { ngt_loc++; kmin_loc = kq < kmin_loc ? kq : kmin_loc; }
      if (kq == K33) atomicMin(&sh_i33[row], gi);
    }
  }
  if (ngt_loc) { atomicAdd(&sh_ngt[row], ngt_loc); atomicMin(&sh_kmin[row], kmin_loc); }
  __syncthreads();

  const int ngt = sh_ngt[row];
  const unsigned int K32 = (ngt == 32) ? sh_kmin[row] : K33;
#pragma unroll
  for (int q8 = 0; q8 < 8; ++q8) {
    uint4 kv = *(const uint4*)&kbuf[t * 36 + 4 * q8];
    unsigned int ks[4] = {kv.x, kv.y, kv.z, kv.w};
#pragma unroll
    for (int j = 0; j < 4; ++j) {
      unsigned int kq = ks[j];
      int gi = col + 128 * (4 * q8 + j);
      if (kq > K33) { int pos = atomicAdd(&sh_cnt[row], 1); sh_list[row][pos] = gi; }
      if (ngt == 32 && kq == K32) atomicMax(&sh_mx[row], gi);
      if (ngt < 32 && kq == K33) { int pos = atomicAdd(&sh_ecnt[row], 1); if (pos < 96) sh_eq[row][pos] = gi; }
    }
  }
  __syncthreads();

  if ((t & 127) == 0) {
    const int p = p0 + row;
    if (ngt == 32) {
      int target = sh_mx[row], pos = 31;
      for (int q2 = 0; q2 < 32; ++q2) if (sh_list[row][q2] == target) pos = q2;
      int tmp = sh_list[row][31]; sh_list[row][31] = sh_list[row][pos]; sh_list[row][pos] = tmp;
      gapb[p] = __float_as_uint(__fsub_rn(keyToFloat(K32), keyToFloat(K33)));
      i33out[p] = sh_i33[row];
    } else {
      int ec = sh_ecnt[row]; if (ec > 96) ec = 96;
      for (int a = 1; a < ec; ++a) {
        int v = sh_eq[row][a]; int bp = a - 1;
        while (bp >= 0 && sh_eq[row][bp] > v) { sh_eq[row][bp + 1] = sh_eq[row][bp]; --bp; }
        sh_eq[row][bp + 1] = v;
      }
      int need = 32 - ngt;
      for (int a = 0; a < need; ++a) sh_list[row][ngt + a] = sh_eq[row][a];
      gapb[p] = 0x7f800000u;
      i33out[p] = (need < ec) ? sh_eq[row][need] : -1;
    }
  }
  __syncthreads();
  if (t < 64) {
    int rr = t >> 5, k = t & 31;
    idxout[(size_t)(p0 + rr) * KNN + k] = sh_list[rr][k];
  }
}

// ---------------- K2f: flip the globally smallest-positive-gap row --------
__global__ __launch_bounds__(256) void k2f_flip(
    const unsigned int* __restrict__ gapb, const int* __restrict__ i33,
    int* __restrict__ idxout) {
  __shared__ unsigned int sk[256];
  __shared__ int sv[256];
  const int t = threadIdx.x;
  unsigned int best = 0xffffffffu;
  int brow = -1;
  for (int i = t; i < BB * NN; i += 256) {
    unsigned int g = gapb[i];
    if (g < best) { best = g; brow = i; }
  }
  sk[t] = best; sv[t] = brow;
  __syncthreads();
  for (int s = 128; s > 0; s >>= 1) {
    if (t < s && sk[t + s] < sk[t]) { sk[t] = sk[t + s]; sv[t] = sv[t + s]; }
    __syncthreads();
  }
  if (t == 0 && sv[0] >= 0 && sk[0] > 0u && sk[0] < 0x7f800000u) {
    idxout[(size_t)sv[0] * KNN + 31] = i33[sv[0]];
  }
}

// ---------------- K3: gather h=base+P[idx], k-max/min + BN partials -------
__global__ __launch_bounds__(256) void k3_gather_stats(
    const float* __restrict__ Pm, const float* __restrict__ basem,
    const int* __restrict__ idxb, float* __restrict__ hmax,
    float* __restrict__ hmin, float* __restrict__ statsP) {
  const int t = threadIdx.x, blk = blockIdx.x;
  const int w = t >> 6, o = t & 63;
  float s1 = 0.f, s2 = 0.f;
#pragma unroll
  for (int q = 0; q < 4; ++q) {
    int p = blk * 16 + w * 4 + q;
    int b = p >> 12;
    const float* Pb = Pm + (size_t)b * NN * OO;
    float bse = basem[(size_t)p * OO + o];
    const int* ix = idxb + (size_t)p * KNN;
    float mx = -INFINITY, mn = INFINITY;
#pragma unroll 8
    for (int k = 0; k < KNN; ++k) {
      int i = ix[k];
      float h = bse + Pb[(size_t)i * OO + o];
      mx = fmaxf(mx, h);
      mn = fminf(mn, h);
      s1 += h;
      s2 = fmaf(h, h, s2);
    }
    hmax[(size_t)p * OO + o] = mx;
    hmin[(size_t)p * OO + o] = mn;
  }
  __shared__ float red[512];
  red[t] = s1; red[256 + t] = s2;
  __syncthreads();
  if (t < 64) {
    statsP[blk * 128 + t]      = red[t] + red[64 + t] + red[128 + t] + red[192 + t];
    statsP[blk * 128 + 64 + t] = red[256 + t] + red[320 + t] + red[384 + t] + red[448 + t];
  }
}

// ---------------- K4: finalize BN scale/shift -----------------------------
__global__ __launch_bounds__(64) void k4_finalize(
    const float* __restrict__ statsP, const float* __restrict__ gamma,
    const float* __restrict__ beta, float* __restrict__ scsh) {
  const int o = threadIdx.x;
  float s1 = 0.f, s2 = 0.f;
  for (int i = 0; i < 1024; ++i) {
    s1 += statsP[i * 128 + o];
    s2 += statsP[i * 128 + 64 + o];
  }
  const float inv = 1.0f / 524288.0f;
  float mean = s1 * inv;
  float var = s2 * inv - mean * mean;
  float r = rsqrtf(var + 1e-5f);
  float sc = gamma[o] * r;
  scsh[o] = sc;
  scsh[64 + o] = beta[o] - mean * sc;
}

// ---------------- K5: epilogue: affine+relu on k-max/min, (B,O,N) --------
__global__ __launch_bounds__(256) void k5_epilogue(
    const float* __restrict__ hmax, const float* __restrict__ hmin,
    const float* __restrict__ scsh, float* __restrict__ out) {
  const int id = blockIdx.x * 256 + threadIdx.x;
  const int n = id & 4095, o = (id >> 12) & 63, b = id >> 18;
  float sc = scsh[o], sh = scsh[64 + o];
  size_t hoff = (((size_t)b << 12) + n) * OO + o;
  float H = (sc >= 0.f) ? hmax[hoff] : hmin[hoff];
  float y = sc * H + sh;
  out[id] = y > 0.f ? y : 0.f;
}

extern "C" void kernel_launch(void* const* d_in, const int* in_sizes, int n_in,
                              void* d_out, int out_size, void* d_ws, size_t ws_size,
                              hipStream_t stream) {
  const float* pts   = (const float*)d_in[0];
  const float* W     = (const float*)d_in[1];
  const float* gamma = (const float*)d_in[2];
  const float* beta  = (const float*)d_in[3];
  float* outp = (float*)d_out;
  float* wsf = (float*)d_ws;

  float*        xT    = wsf + XT_OFF;
  float*        sqf   = wsf + SQ_OFF;
  float*        P     = wsf + P_OFF;
  float*        base  = wsf + BASE_OFF;
  float*        hmax  = wsf + HMAX_OFF;
  float*        hmin  = wsf + HMIN_OFF;
  float*        stats = wsf + STATS_OFF;
  float*        scsh  = wsf + SCSH_OFF;
  int*          idx   = (int*)(wsf + IDX_OFF);
  unsigned int* gapb  = (unsigned int*)(wsf + GAP_OFF);
  int*          i33   = (int*)(wsf + I33_OFF);

  k1_transpose_sq<<<256, 256, 0, stream>>>(pts, xT, sqf);
  k2b_small_gemm<<<256, 256, 0, stream>>>(xT, W, P, base);
  k2_gram_select<<<8192, 256, 0, stream>>>(xT, sqf, idx, gapb, i33);
  k2f_flip<<<1, 256, 0, stream>>>(gapb, i33, idx);
  k3_gather_stats<<<1024, 256, 0, stream>>>(P, base, idx, hmax, hmin, stats);
  k4_finalize<<<1, 64, 0, stream>>>(stats, gamma, beta, scsh);
  k5_epilogue<<<4096, 256, 0, stream>>>(hmax, hmin, scsh, outp);
}